// Round 1
// baseline (889.531 us; speedup 1.0000x reference)
//
#include <hip/hip_runtime.h>
#include <hip/hip_bf16.h>

#define CIN  128
#define FOUT 128
#define HID  32
#define EPSV 1e-8f

// ---------------------------------------------------------------------------
// Per-vertex: h = relu(f@W1+b1); M = h@W2+b2 (3x3); G = M^T M; xw = f@Wc
// One block (128 threads) per vertex. Feature row staged in LDS.
// ---------------------------------------------------------------------------
__global__ void vertex_kernel(const float* __restrict__ feat,
                              const float* __restrict__ W1,
                              const float* __restrict__ b1,
                              const float* __restrict__ W2,
                              const float* __restrict__ b2,
                              const float* __restrict__ Wc,
                              float* __restrict__ G,
                              float* __restrict__ xw) {
    __shared__ float f[CIN];
    __shared__ float h[HID];
    __shared__ float M[9];
    const int v = blockIdx.x;
    const int t = threadIdx.x;

    f[t] = feat[(size_t)v * CIN + t];
    __syncthreads();

    // xw row: thread t computes output feature t (dot over 128)
    float acc = 0.f;
#pragma unroll 8
    for (int c = 0; c < CIN; ++c)
        acc = fmaf(f[c], Wc[c * FOUT + t], acc);
    xw[(size_t)v * FOUT + t] = acc;

    // hidden layer
    if (t < HID) {
        float a = b1[t];
#pragma unroll 8
        for (int c = 0; c < CIN; ++c)
            a = fmaf(f[c], W1[c * HID + t], a);
        h[t] = fmaxf(a, 0.f);
    }
    __syncthreads();

    // M = h@W2 + b2  (9 outputs)
    if (t < 9) {
        float m = b2[t];
#pragma unroll
        for (int j = 0; j < HID; ++j)
            m = fmaf(h[j], W2[j * 9 + t], m);
        M[t] = m;
    }
    __syncthreads();

    // G = M^T M  (G[i][j] = sum_k M[k,i]*M[k,j]; M flat is [k*3+i])
    if (t < 9) {
        const int i = t / 3, j = t % 3;
        float g = 0.f;
#pragma unroll
        for (int k = 0; k < 3; ++k)
            g += M[k * 3 + i] * M[k * 3 + j];
        G[(size_t)v * 9 + t] = g;
    }
}

// ---------------------------------------------------------------------------
// Per-edge: t = v[dst]-v[src]; q = 0.5 * t^T (G[src]+G[dst]) t; w = exp(-q)
// Also accumulates rowsum[src] via atomics.
// ---------------------------------------------------------------------------
__global__ void edge_kernel(const int* __restrict__ edges,   // [2, E] flat
                            const float* __restrict__ verts, // [N, 3]
                            const float* __restrict__ G,     // [N, 9]
                            float* __restrict__ wbuf,        // [E]
                            float* __restrict__ rowsum,      // [N]
                            int E) {
    const int e = blockIdx.x * blockDim.x + threadIdx.x;
    if (e >= E) return;
    const int s = edges[e];
    const int d = edges[E + e];

    float tv[3];
#pragma unroll
    for (int i = 0; i < 3; ++i)
        tv[i] = verts[d * 3 + i] - verts[s * 3 + i];

    const float* Gs = G + (size_t)s * 9;
    const float* Gd = G + (size_t)d * 9;
    float q = 0.f;
#pragma unroll
    for (int i = 0; i < 3; ++i) {
#pragma unroll
        for (int j = 0; j < 3; ++j)
            q += (Gs[i * 3 + j] + Gd[i * 3 + j]) * tv[i] * tv[j];
    }
    q *= 0.5f;
    const float w = expf(-q);
    wbuf[e] = w;
    atomicAdd(&rowsum[s], w);
}

// ---------------------------------------------------------------------------
// Per-edge message scatter: out[src,:] += w * xw[dst,:]
// One wave (64 lanes) per edge; each lane handles 2 features (float2 load).
// ---------------------------------------------------------------------------
__global__ void msg_kernel(const int* __restrict__ edges,
                           const float* __restrict__ wbuf,
                           const float* __restrict__ xw,
                           float* __restrict__ outacc,
                           int E) {
    const int wid  = (int)((blockIdx.x * (size_t)blockDim.x + threadIdx.x) >> 6);
    const int lane = threadIdx.x & 63;
    if (wid >= E) return;
    const int s = edges[wid];
    const int d = edges[E + wid];
    const float w = wbuf[wid];
    const float2 v = ((const float2*)(xw + (size_t)d * FOUT))[lane];
    float* o = outacc + (size_t)s * FOUT + 2 * lane;
    atomicAdd(o,     w * v.x);
    atomicAdd(o + 1, w * v.y);
}

// ---------------------------------------------------------------------------
// Finalize: out = out / (rowsum + eps) + bias
// ---------------------------------------------------------------------------
__global__ void fin_kernel(float* __restrict__ out,
                           const float* __restrict__ rowsum,
                           const float* __restrict__ bias,
                           int total) {
    const int idx = blockIdx.x * blockDim.x + threadIdx.x;
    if (idx >= total) return;
    const int v = idx >> 7;           // / FOUT
    const int f = idx & (FOUT - 1);   // % FOUT
    out[idx] = out[idx] / (rowsum[v] + EPSV) + bias[f];
}

extern "C" void kernel_launch(void* const* d_in, const int* in_sizes, int n_in,
                              void* d_out, int out_size, void* d_ws, size_t ws_size,
                              hipStream_t stream) {
    const float* feat  = (const float*)d_in[0];
    const float* verts = (const float*)d_in[1];
    const int*   edges = (const int*)d_in[2];
    // d_in[3] = faces (unused by reference)
    const float* W1    = (const float*)d_in[4];
    const float* b1    = (const float*)d_in[5];
    const float* W2    = (const float*)d_in[6];
    const float* b2    = (const float*)d_in[7];
    const float* Wc    = (const float*)d_in[8];
    const float* bias  = (const float*)d_in[9];

    const int N = in_sizes[0] / CIN;
    const int E = in_sizes[2] / 2;

    float* ws     = (float*)d_ws;
    float* xw     = ws;                         // N*FOUT
    float* G      = xw + (size_t)N * FOUT;      // N*9
    float* wbuf   = G + (size_t)N * 9;          // E
    float* rowsum = wbuf + E;                   // N
    float* out    = (float*)d_out;

    hipMemsetAsync(out, 0, (size_t)N * FOUT * sizeof(float), stream);
    hipMemsetAsync(rowsum, 0, (size_t)N * sizeof(float), stream);

    vertex_kernel<<<N, CIN, 0, stream>>>(feat, W1, b1, W2, b2, Wc, G, xw);
    edge_kernel<<<(E + 255) / 256, 256, 0, stream>>>(edges, verts, G, wbuf, rowsum, E);
    msg_kernel<<<(E + 3) / 4, 256, 0, stream>>>(edges, wbuf, xw, out, E);
    fin_kernel<<<(N * FOUT + 255) / 256, 256, 0, stream>>>(out, rowsum, bias, N * FOUT);
}

// Round 2
// 312.655 us; speedup vs baseline: 2.8451x; 2.8451x over previous
//
#include <hip/hip_runtime.h>
#include <hip/hip_bf16.h>

#define CIN  128
#define FOUT 128
#define HID  32
#define EPSV 1e-8f

// ---------------------------------------------------------------------------
// Per-vertex: h = relu(f@W1+b1); M = h@W2+b2 (3x3); G = M^T M; xw = f@Wc
// One block (128 threads) per vertex. Feature row staged in LDS.
// ---------------------------------------------------------------------------
__global__ void vertex_kernel(const float* __restrict__ feat,
                              const float* __restrict__ W1,
                              const float* __restrict__ b1,
                              const float* __restrict__ W2,
                              const float* __restrict__ b2,
                              const float* __restrict__ Wc,
                              float* __restrict__ G,
                              float* __restrict__ xw) {
    __shared__ float f[CIN];
    __shared__ float h[HID];
    __shared__ float M[9];
    const int v = blockIdx.x;
    const int t = threadIdx.x;

    f[t] = feat[(size_t)v * CIN + t];
    __syncthreads();

    // xw row: thread t computes output feature t (dot over 128)
    float acc = 0.f;
#pragma unroll 8
    for (int c = 0; c < CIN; ++c)
        acc = fmaf(f[c], Wc[c * FOUT + t], acc);
    xw[(size_t)v * FOUT + t] = acc;

    // hidden layer
    if (t < HID) {
        float a = b1[t];
#pragma unroll 8
        for (int c = 0; c < CIN; ++c)
            a = fmaf(f[c], W1[c * HID + t], a);
        h[t] = fmaxf(a, 0.f);
    }
    __syncthreads();

    // M = h@W2 + b2  (9 outputs)
    if (t < 9) {
        float m = b2[t];
#pragma unroll
        for (int j = 0; j < HID; ++j)
            m = fmaf(h[j], W2[j * 9 + t], m);
        M[t] = m;
    }
    __syncthreads();

    // G = M^T M  (G[i][j] = sum_k M[k,i]*M[k,j]; M flat is [k*3+i])
    if (t < 9) {
        const int i = t / 3, j = t % 3;
        float g = 0.f;
#pragma unroll
        for (int k = 0; k < 3; ++k)
            g += M[k * 3 + i] * M[k * 3 + j];
        G[(size_t)v * 9 + t] = g;
    }
}

// ---------------------------------------------------------------------------
// CSR build step 1: histogram of src
// ---------------------------------------------------------------------------
__global__ void hist_kernel(const int* __restrict__ edges, int* __restrict__ counts, int E) {
    const int e = blockIdx.x * blockDim.x + threadIdx.x;
    if (e < E) atomicAdd(&counts[edges[e]], 1);
}

// ---------------------------------------------------------------------------
// CSR build step 2a: per-256-block sums of counts
// ---------------------------------------------------------------------------
__global__ void blocksum_kernel(const int* __restrict__ counts, int* __restrict__ bsums, int N) {
    __shared__ int s[256];
    const int i = blockIdx.x * 256 + threadIdx.x;
    s[threadIdx.x] = (i < N) ? counts[i] : 0;
    __syncthreads();
    for (int st = 128; st > 0; st >>= 1) {
        if (threadIdx.x < st) s[threadIdx.x] += s[threadIdx.x + st];
        __syncthreads();
    }
    if (threadIdx.x == 0) bsums[blockIdx.x] = s[0];
}

// ---------------------------------------------------------------------------
// CSR build step 2b: exclusive scan of block sums (single block; nb <= 256)
// ---------------------------------------------------------------------------
__global__ void scanb_kernel(const int* __restrict__ bsums, int* __restrict__ bpre, int nb) {
    __shared__ int s[256];
    const int t = threadIdx.x;
    const int v0 = (t < nb) ? bsums[t] : 0;
    s[t] = v0;
    __syncthreads();
    for (int off = 1; off < 256; off <<= 1) {
        int v = (t >= off) ? s[t - off] : 0;
        __syncthreads();
        s[t] += v;
        __syncthreads();
    }
    if (t < nb) bpre[t] = s[t] - v0;   // exclusive
}

// ---------------------------------------------------------------------------
// CSR build step 2c: per-element exclusive scan within block + block prefix
// ---------------------------------------------------------------------------
__global__ void offsets_kernel(const int* __restrict__ counts, const int* __restrict__ bpre,
                               int* __restrict__ offset, int* __restrict__ cursor, int N) {
    __shared__ int s[256];
    const int i = blockIdx.x * 256 + threadIdx.x;
    const int c = (i < N) ? counts[i] : 0;
    s[threadIdx.x] = c;
    __syncthreads();
    for (int off = 1; off < 256; off <<= 1) {
        int v = (threadIdx.x >= off) ? s[threadIdx.x - off] : 0;
        __syncthreads();
        s[threadIdx.x] += v;
        __syncthreads();
    }
    if (i < N) {
        const int excl = bpre[blockIdx.x] + s[threadIdx.x] - c;
        offset[i] = excl;
        cursor[i] = excl;
    }
}

// ---------------------------------------------------------------------------
// CSR build step 3: fill — compute edge weight w and drop (dst, w) into the
// src-bucket slot. G is 1.8 MB -> L2-resident gathers.
// ---------------------------------------------------------------------------
__global__ void fill_kernel(const int* __restrict__ edges,
                            const float* __restrict__ verts,
                            const float* __restrict__ G,
                            int* __restrict__ cursor,
                            int* __restrict__ dst_r,
                            float* __restrict__ w_r,
                            int E) {
    const int e = blockIdx.x * blockDim.x + threadIdx.x;
    if (e >= E) return;
    const int s = edges[e];
    const int d = edges[E + e];

    float tv[3];
#pragma unroll
    for (int i = 0; i < 3; ++i)
        tv[i] = verts[d * 3 + i] - verts[s * 3 + i];

    const float* Gs = G + (size_t)s * 9;
    const float* Gd = G + (size_t)d * 9;
    float q = 0.f;
#pragma unroll
    for (int i = 0; i < 3; ++i)
#pragma unroll
        for (int j = 0; j < 3; ++j)
            q += (Gs[i * 3 + j] + Gd[i * 3 + j]) * tv[i] * tv[j];
    const float w = expf(-0.5f * q);

    const int slot = atomicAdd(&cursor[s], 1);
    dst_r[slot] = d;
    w_r[slot] = w;
}

// ---------------------------------------------------------------------------
// Gather-side aggregation: one wave per vertex. Lane l owns cols {2l, 2l+1}.
// out[v,:] = (sum_k w_k * xw[dst_k,:]) / (sum_k w_k + eps) + bias
// ---------------------------------------------------------------------------
__global__ __launch_bounds__(256) void agg_kernel(const int* __restrict__ offset,
                                                  const int* __restrict__ counts,
                                                  const int* __restrict__ dst_r,
                                                  const float* __restrict__ w_r,
                                                  const float* __restrict__ xw,
                                                  const float* __restrict__ bias,
                                                  float* __restrict__ out,
                                                  int N) {
    const int wid  = threadIdx.x >> 6;
    const int lane = threadIdx.x & 63;
    const int v = blockIdx.x * 4 + wid;
    if (v >= N) return;

    const int beg = offset[v];
    const int deg = counts[v];

    float ax = 0.f, ay = 0.f, wsum = 0.f;
    int k = 0;
    for (; k + 2 <= deg; k += 2) {
        const int   d0 = dst_r[beg + k];
        const float w0 = w_r[beg + k];
        const int   d1 = dst_r[beg + k + 1];
        const float w1 = w_r[beg + k + 1];
        const float2 x0 = ((const float2*)(xw + (size_t)d0 * FOUT))[lane];
        const float2 x1 = ((const float2*)(xw + (size_t)d1 * FOUT))[lane];
        ax = fmaf(w0, x0.x, ax); ay = fmaf(w0, x0.y, ay);
        ax = fmaf(w1, x1.x, ax); ay = fmaf(w1, x1.y, ay);
        wsum += w0 + w1;
    }
    if (k < deg) {
        const int   d0 = dst_r[beg + k];
        const float w0 = w_r[beg + k];
        const float2 x0 = ((const float2*)(xw + (size_t)d0 * FOUT))[lane];
        ax = fmaf(w0, x0.x, ax); ay = fmaf(w0, x0.y, ay);
        wsum += w0;
    }

    const float inv = 1.f / (wsum + EPSV);
    const float2 b = ((const float2*)bias)[lane];
    float2 o;
    o.x = ax * inv + b.x;
    o.y = ay * inv + b.y;
    ((float2*)(out + (size_t)v * FOUT))[lane] = o;
}

extern "C" void kernel_launch(void* const* d_in, const int* in_sizes, int n_in,
                              void* d_out, int out_size, void* d_ws, size_t ws_size,
                              hipStream_t stream) {
    const float* feat  = (const float*)d_in[0];
    const float* verts = (const float*)d_in[1];
    const int*   edges = (const int*)d_in[2];
    // d_in[3] = faces (unused by reference)
    const float* W1    = (const float*)d_in[4];
    const float* b1    = (const float*)d_in[5];
    const float* W2    = (const float*)d_in[6];
    const float* b2    = (const float*)d_in[7];
    const float* Wc    = (const float*)d_in[8];
    const float* bias  = (const float*)d_in[9];

    const int N = in_sizes[0] / CIN;
    const int E = in_sizes[2] / 2;
    const int nb = (N + 255) / 256;

    // workspace layout
    float* xw   = (float*)d_ws;                 // N*FOUT floats
    float* G    = xw + (size_t)N * FOUT;        // N*9
    float* w_r  = G + (size_t)N * 9;            // E
    int* counts = (int*)(w_r + E);              // N
    int* offset = counts + N;                   // N
    int* cursor = offset + N;                   // N
    int* bsums  = cursor + N;                   // nb (<=256)
    int* bpre   = bsums + 256;                  // nb (<=256)
    int* dst_r  = bpre + 256;                   // E
    float* out  = (float*)d_out;

    hipMemsetAsync(counts, 0, (size_t)N * sizeof(int), stream);

    vertex_kernel<<<N, CIN, 0, stream>>>(feat, W1, b1, W2, b2, Wc, G, xw);
    hist_kernel<<<(E + 255) / 256, 256, 0, stream>>>(edges, counts, E);
    blocksum_kernel<<<nb, 256, 0, stream>>>(counts, bsums, N);
    scanb_kernel<<<1, 256, 0, stream>>>(bsums, bpre, nb);
    offsets_kernel<<<nb, 256, 0, stream>>>(counts, bpre, offset, cursor, N);
    fill_kernel<<<(E + 255) / 256, 256, 0, stream>>>(edges, verts, G, cursor, dst_r, w_r, E);
    agg_kernel<<<(N + 3) / 4, 256, 0, stream>>>(offset, counts, dst_r, w_r, xw, bias, out, N);
}

// Round 3
// 187.910 us; speedup vs baseline: 4.7338x; 1.6639x over previous
//
#include <hip/hip_runtime.h>
#include <hip/hip_bf16.h>

#define CIN  128
#define FOUT 128
#define HID  32
#define EPSV 1e-8f

typedef __attribute__((ext_vector_type(8))) short bf16x8;
typedef __attribute__((ext_vector_type(4))) float f32x4;

__device__ inline short f2bf(float x) {
    union { float f; unsigned u; } v; v.f = x;
    unsigned r = v.u + 0x7fffu + ((v.u >> 16) & 1u);
    return (short)(r >> 16);
}
__device__ inline float bfbits2f(unsigned b) {
    union { unsigned u; float f; } v; v.u = b << 16;
    return v.f;
}

// ---------------------------------------------------------------------------
// Prep: transpose + bf16-convert Wc -> WcT [FOUT][CIN], W1 -> W1T [HID][CIN]
// ---------------------------------------------------------------------------
__global__ void prep_kernel(const float* __restrict__ Wc,
                            const float* __restrict__ W1,
                            short* __restrict__ WcT,
                            short* __restrict__ W1T) {
    const int idx = blockIdx.x * 256 + threadIdx.x;
    if (idx < CIN * FOUT) {
        const int c = idx >> 7, k = idx & 127;
        WcT[c * CIN + k] = f2bf(Wc[k * FOUT + c]);
    }
    if (idx < HID * CIN) {
        const int c = idx >> 7, k = idx & 127;
        W1T[c * CIN + k] = f2bf(W1[k * HID + c]);
    }
}

// ---------------------------------------------------------------------------
// Per-16-vertex wave: MFMA xw = feat@Wc (bf16), h = relu(feat@W1+b1) (bf16),
// then M = h@W2+b2 and G = M^T M in fp32 via LDS.
// ---------------------------------------------------------------------------
__global__ __launch_bounds__(256) void vertex_mfma(
    const float* __restrict__ feat,
    const short* __restrict__ WcT,    // [FOUT][CIN] bf16
    const short* __restrict__ W1T,    // [HID][CIN] bf16
    const float* __restrict__ b1,
    const float* __restrict__ W2,     // [HID][9]
    const float* __restrict__ b2,
    float* __restrict__ G,            // [N][9]
    unsigned short* __restrict__ xwb, // [N][FOUT] bf16 bits
    int N) {
    __shared__ float h_lds[4][16][HID];
    __shared__ float M_lds[4][16][9];
    const int wid  = threadIdx.x >> 6;
    const int lane = threadIdx.x & 63;
    const int v0   = (blockIdx.x * 4 + wid) * 16;
    const int r    = lane & 15;
    const int hi   = lane >> 4;
    const int vr   = min(v0 + r, N - 1);

    // A fragments: 4 k-tiles of 32; lane holds feat[vr][kt*32 + hi*8 .. +8]
    bf16x8 a[4];
#pragma unroll
    for (int kt = 0; kt < 4; ++kt) {
        const float* src = feat + (size_t)vr * CIN + kt * 32 + hi * 8;
        const float4 f0 = ((const float4*)src)[0];
        const float4 f1 = ((const float4*)src)[1];
        bf16x8 t;
        t[0] = f2bf(f0.x); t[1] = f2bf(f0.y); t[2] = f2bf(f0.z); t[3] = f2bf(f0.w);
        t[4] = f2bf(f1.x); t[5] = f2bf(f1.y); t[6] = f2bf(f1.z); t[7] = f2bf(f1.w);
        a[kt] = t;
    }

    // xw: 8 column tiles of 16
#pragma unroll
    for (int ct = 0; ct < 8; ++ct) {
        f32x4 acc = {0.f, 0.f, 0.f, 0.f};
#pragma unroll
        for (int kt = 0; kt < 4; ++kt) {
            const bf16x8 b = *((const bf16x8*)(WcT + (size_t)(ct * 16 + r) * CIN + kt * 32 + hi * 8));
            acc = __builtin_amdgcn_mfma_f32_16x16x32_bf16(a[kt], b, acc, 0, 0, 0);
        }
#pragma unroll
        for (int reg = 0; reg < 4; ++reg) {
            const int row = hi * 4 + reg;
            if (v0 + row < N)
                xwb[(size_t)(v0 + row) * FOUT + ct * 16 + r] = (unsigned short)f2bf(acc[reg]);
        }
    }

    // h: 2 column tiles of 16 over W1T
#pragma unroll
    for (int ct = 0; ct < 2; ++ct) {
        f32x4 acc = {0.f, 0.f, 0.f, 0.f};
#pragma unroll
        for (int kt = 0; kt < 4; ++kt) {
            const bf16x8 b = *((const bf16x8*)(W1T + (size_t)(ct * 16 + r) * CIN + kt * 32 + hi * 8));
            acc = __builtin_amdgcn_mfma_f32_16x16x32_bf16(a[kt], b, acc, 0, 0, 0);
        }
        const float bb = b1[ct * 16 + r];
#pragma unroll
        for (int reg = 0; reg < 4; ++reg)
            h_lds[wid][hi * 4 + reg][ct * 16 + r] = fmaxf(acc[reg] + bb, 0.f);
    }
    __syncthreads();

    // M = h @ W2 + b2  (16 verts x 9 outputs per wave)
    for (int idx = lane; idx < 144; idx += 64) {
        const int v = idx / 9, t = idx - v * 9;
        float m = b2[t];
#pragma unroll
        for (int k = 0; k < HID; ++k)
            m = fmaf(h_lds[wid][v][k], W2[k * 9 + t], m);
        M_lds[wid][v][t] = m;
    }
    __syncthreads();

    // G = M^T M
    for (int idx = lane; idx < 144; idx += 64) {
        const int v = idx / 9, t = idx - v * 9;
        const int i = t / 3, j = t - i * 3;
        float g = 0.f;
#pragma unroll
        for (int k = 0; k < 3; ++k)
            g += M_lds[wid][v][k * 3 + i] * M_lds[wid][v][k * 3 + j];
        if (v0 + v < N) G[(size_t)(v0 + v) * 9 + t] = g;
    }
}

// ---------------------------------------------------------------------------
// CSR build step 1: histogram of src
// ---------------------------------------------------------------------------
__global__ void hist_kernel(const int* __restrict__ edges, int* __restrict__ counts, int E) {
    const int e = blockIdx.x * blockDim.x + threadIdx.x;
    if (e < E) atomicAdd(&counts[edges[e]], 1);
}

__global__ void blocksum_kernel(const int* __restrict__ counts, int* __restrict__ bsums, int N) {
    __shared__ int s[256];
    const int i = blockIdx.x * 256 + threadIdx.x;
    s[threadIdx.x] = (i < N) ? counts[i] : 0;
    __syncthreads();
    for (int st = 128; st > 0; st >>= 1) {
        if (threadIdx.x < st) s[threadIdx.x] += s[threadIdx.x + st];
        __syncthreads();
    }
    if (threadIdx.x == 0) bsums[blockIdx.x] = s[0];
}

__global__ void scanb_kernel(const int* __restrict__ bsums, int* __restrict__ bpre, int nb) {
    __shared__ int s[256];
    const int t = threadIdx.x;
    const int v0 = (t < nb) ? bsums[t] : 0;
    s[t] = v0;
    __syncthreads();
    for (int off = 1; off < 256; off <<= 1) {
        int v = (t >= off) ? s[t - off] : 0;
        __syncthreads();
        s[t] += v;
        __syncthreads();
    }
    if (t < nb) bpre[t] = s[t] - v0;
}

__global__ void offsets_kernel(const int* __restrict__ counts, const int* __restrict__ bpre,
                               int* __restrict__ offset, int* __restrict__ cursor, int N) {
    __shared__ int s[256];
    const int i = blockIdx.x * 256 + threadIdx.x;
    const int c = (i < N) ? counts[i] : 0;
    s[threadIdx.x] = c;
    __syncthreads();
    for (int off = 1; off < 256; off <<= 1) {
        int v = (threadIdx.x >= off) ? s[threadIdx.x - off] : 0;
        __syncthreads();
        s[threadIdx.x] += v;
        __syncthreads();
    }
    if (i < N) {
        const int excl = bpre[blockIdx.x] + s[threadIdx.x] - c;
        offset[i] = excl;
        cursor[i] = excl;
    }
}

// ---------------------------------------------------------------------------
// CSR fill: edge weight w + (dst, w) into src bucket
// ---------------------------------------------------------------------------
__global__ void fill_kernel(const int* __restrict__ edges,
                            const float* __restrict__ verts,
                            const float* __restrict__ G,
                            int* __restrict__ cursor,
                            int* __restrict__ dst_r,
                            float* __restrict__ w_r,
                            int E) {
    const int e = blockIdx.x * blockDim.x + threadIdx.x;
    if (e >= E) return;
    const int s = edges[e];
    const int d = edges[E + e];

    float tv[3];
#pragma unroll
    for (int i = 0; i < 3; ++i)
        tv[i] = verts[d * 3 + i] - verts[s * 3 + i];

    const float* Gs = G + (size_t)s * 9;
    const float* Gd = G + (size_t)d * 9;
    float q = 0.f;
#pragma unroll
    for (int i = 0; i < 3; ++i)
#pragma unroll
        for (int j = 0; j < 3; ++j)
            q += (Gs[i * 3 + j] + Gd[i * 3 + j]) * tv[i] * tv[j];
    const float w = expf(-0.5f * q);

    const int slot = atomicAdd(&cursor[s], 1);
    dst_r[slot] = d;
    w_r[slot] = w;
}

// ---------------------------------------------------------------------------
// Gather aggregation: one wave per vertex; lane l owns cols {2l, 2l+1}.
// xw rows are bf16.
// ---------------------------------------------------------------------------
__global__ __launch_bounds__(256) void agg_kernel(const int* __restrict__ offset,
                                                  const int* __restrict__ counts,
                                                  const int* __restrict__ dst_r,
                                                  const float* __restrict__ w_r,
                                                  const unsigned short* __restrict__ xwb,
                                                  const float* __restrict__ bias,
                                                  float* __restrict__ out,
                                                  int N) {
    const int wid  = threadIdx.x >> 6;
    const int lane = threadIdx.x & 63;
    const int v = blockIdx.x * 4 + wid;
    if (v >= N) return;

    const int beg = offset[v];
    const int deg = counts[v];

    float ax = 0.f, ay = 0.f, wsum = 0.f;
    int k = 0;
    for (; k + 2 <= deg; k += 2) {
        const int   d0 = dst_r[beg + k];
        const float w0 = w_r[beg + k];
        const int   d1 = dst_r[beg + k + 1];
        const float w1 = w_r[beg + k + 1];
        const unsigned u0 = ((const unsigned*)(xwb + (size_t)d0 * FOUT))[lane];
        const unsigned u1 = ((const unsigned*)(xwb + (size_t)d1 * FOUT))[lane];
        ax = fmaf(w0, bfbits2f(u0 & 0xffffu), ax);
        ay = fmaf(w0, bfbits2f(u0 >> 16), ay);
        ax = fmaf(w1, bfbits2f(u1 & 0xffffu), ax);
        ay = fmaf(w1, bfbits2f(u1 >> 16), ay);
        wsum += w0 + w1;
    }
    if (k < deg) {
        const int   d0 = dst_r[beg + k];
        const float w0 = w_r[beg + k];
        const unsigned u0 = ((const unsigned*)(xwb + (size_t)d0 * FOUT))[lane];
        ax = fmaf(w0, bfbits2f(u0 & 0xffffu), ax);
        ay = fmaf(w0, bfbits2f(u0 >> 16), ay);
        wsum += w0;
    }

    const float inv = 1.f / (wsum + EPSV);
    const float2 b = ((const float2*)bias)[lane];
    float2 o;
    o.x = ax * inv + b.x;
    o.y = ay * inv + b.y;
    ((float2*)(out + (size_t)v * FOUT))[lane] = o;
}

extern "C" void kernel_launch(void* const* d_in, const int* in_sizes, int n_in,
                              void* d_out, int out_size, void* d_ws, size_t ws_size,
                              hipStream_t stream) {
    const float* feat  = (const float*)d_in[0];
    const float* verts = (const float*)d_in[1];
    const int*   edges = (const int*)d_in[2];
    // d_in[3] = faces (unused)
    const float* W1    = (const float*)d_in[4];
    const float* b1    = (const float*)d_in[5];
    const float* W2    = (const float*)d_in[6];
    const float* b2    = (const float*)d_in[7];
    const float* Wc    = (const float*)d_in[8];
    const float* bias  = (const float*)d_in[9];

    const int N = in_sizes[0] / CIN;
    const int E = in_sizes[2] / 2;
    const int nb = (N + 255) / 256;

    // workspace layout (256B-aligned chunks)
    char* p = (char*)d_ws;
    auto alloc = [&](size_t bytes) {
        char* r = p;
        p += (bytes + 255) & ~(size_t)255;
        return r;
    };
    short*          WcT    = (short*)alloc((size_t)CIN * FOUT * sizeof(short));
    short*          W1T    = (short*)alloc((size_t)HID * CIN * sizeof(short));
    unsigned short* xwb    = (unsigned short*)alloc((size_t)N * FOUT * sizeof(short));
    float*          G      = (float*)alloc((size_t)N * 9 * sizeof(float));
    float*          w_r    = (float*)alloc((size_t)E * sizeof(float));
    int*            dst_r  = (int*)alloc((size_t)E * sizeof(int));
    int*            counts = (int*)alloc((size_t)N * sizeof(int));
    int*            offset = (int*)alloc((size_t)N * sizeof(int));
    int*            cursor = (int*)alloc((size_t)N * sizeof(int));
    int*            bsums  = (int*)alloc(256 * sizeof(int));
    int*            bpre   = (int*)alloc(256 * sizeof(int));
    float*          out    = (float*)d_out;

    hipMemsetAsync(counts, 0, (size_t)N * sizeof(int), stream);

    prep_kernel<<<64, 256, 0, stream>>>(Wc, W1, WcT, W1T);

    const int nwaves = (N + 15) / 16;
    vertex_mfma<<<(nwaves + 3) / 4, 256, 0, stream>>>(feat, WcT, W1T, b1, W2, b2, G, xwb, N);

    hist_kernel<<<(E + 255) / 256, 256, 0, stream>>>(edges, counts, E);
    blocksum_kernel<<<nb, 256, 0, stream>>>(counts, bsums, N);
    scanb_kernel<<<1, 256, 0, stream>>>(bsums, bpre, nb);
    offsets_kernel<<<nb, 256, 0, stream>>>(counts, bpre, offset, cursor, N);
    fill_kernel<<<(E + 255) / 256, 256, 0, stream>>>(edges, verts, G, cursor, dst_r, w_r, E);
    agg_kernel<<<(N + 3) / 4, 256, 0, stream>>>(offset, counts, dst_r, w_r, xwb, bias, out, N);
}

// Round 4
// 157.238 us; speedup vs baseline: 5.6572x; 1.1951x over previous
//
#include <hip/hip_runtime.h>
#include <hip/hip_bf16.h>

#define CIN  128
#define FOUT 128
#define HID  32
#define EPSV 1e-8f

typedef __attribute__((ext_vector_type(8))) short bf16x8;
typedef __attribute__((ext_vector_type(4))) float f32x4;

__device__ inline short f2bf(float x) {
    union { float f; unsigned u; } v; v.f = x;
    unsigned r = v.u + 0x7fffu + ((v.u >> 16) & 1u);
    return (short)(r >> 16);
}
__device__ inline float bfbits2f(unsigned b) {
    union { unsigned u; float f; } v; v.u = b << 16;
    return v.f;
}

// ---------------------------------------------------------------------------
// Prep: WcT/W1T bf16 transposes, padded verts [N][4], zero counts.
// ---------------------------------------------------------------------------
__global__ void prep_kernel(const float* __restrict__ Wc,
                            const float* __restrict__ W1,
                            const float* __restrict__ verts,
                            short* __restrict__ WcT,
                            short* __restrict__ W1T,
                            float* __restrict__ vertsP,
                            int* __restrict__ counts,
                            int N) {
    const int idx = blockIdx.x * 256 + threadIdx.x;
    if (idx < CIN * FOUT) {
        const int c = idx >> 7, k = idx & 127;
        WcT[c * CIN + k] = f2bf(Wc[k * FOUT + c]);
    }
    if (idx < HID * CIN) {
        const int c = idx >> 7, k = idx & 127;
        W1T[c * CIN + k] = f2bf(W1[k * HID + c]);
    }
    if (idx < N) {
        vertsP[idx * 4 + 0] = verts[idx * 3 + 0];
        vertsP[idx * 4 + 1] = verts[idx * 3 + 1];
        vertsP[idx * 4 + 2] = verts[idx * 3 + 2];
        vertsP[idx * 4 + 3] = 0.f;
        counts[idx] = 0;
    }
}

// ---------------------------------------------------------------------------
// Per-16-vertex wave: MFMA xw = feat@Wc (bf16), h = relu(feat@W1+b1),
// then M = h@W2+b2 and packed symmetric G = M^T M (6 vals, stride 8).
// ---------------------------------------------------------------------------
__global__ __launch_bounds__(256) void vertex_mfma(
    const float* __restrict__ feat,
    const short* __restrict__ WcT,    // [FOUT][CIN] bf16
    const short* __restrict__ W1T,    // [HID][CIN] bf16
    const float* __restrict__ b1,
    const float* __restrict__ W2,     // [HID][9]
    const float* __restrict__ b2,
    float* __restrict__ Gp,           // [N][8] packed symmetric
    unsigned short* __restrict__ xwb, // [N][FOUT] bf16 bits
    int N) {
    __shared__ float h_lds[4][16][HID];
    __shared__ float M_lds[4][16][9];
    const int wid  = threadIdx.x >> 6;
    const int lane = threadIdx.x & 63;
    const int v0   = (blockIdx.x * 4 + wid) * 16;
    const int r    = lane & 15;
    const int hi   = lane >> 4;
    const int vr   = min(v0 + r, N - 1);

    // A fragments: 4 k-tiles of 32; lane holds feat[vr][kt*32 + hi*8 .. +8]
    bf16x8 a[4];
#pragma unroll
    for (int kt = 0; kt < 4; ++kt) {
        const float* src = feat + (size_t)vr * CIN + kt * 32 + hi * 8;
        const float4 f0 = ((const float4*)src)[0];
        const float4 f1 = ((const float4*)src)[1];
        bf16x8 t;
        t[0] = f2bf(f0.x); t[1] = f2bf(f0.y); t[2] = f2bf(f0.z); t[3] = f2bf(f0.w);
        t[4] = f2bf(f1.x); t[5] = f2bf(f1.y); t[6] = f2bf(f1.z); t[7] = f2bf(f1.w);
        a[kt] = t;
    }

    // xw: 8 column tiles of 16
#pragma unroll
    for (int ct = 0; ct < 8; ++ct) {
        f32x4 acc = {0.f, 0.f, 0.f, 0.f};
#pragma unroll
        for (int kt = 0; kt < 4; ++kt) {
            const bf16x8 b = *((const bf16x8*)(WcT + (size_t)(ct * 16 + r) * CIN + kt * 32 + hi * 8));
            acc = __builtin_amdgcn_mfma_f32_16x16x32_bf16(a[kt], b, acc, 0, 0, 0);
        }
#pragma unroll
        for (int reg = 0; reg < 4; ++reg) {
            const int row = hi * 4 + reg;
            if (v0 + row < N)
                xwb[(size_t)(v0 + row) * FOUT + ct * 16 + r] = (unsigned short)f2bf(acc[reg]);
        }
    }

    // h: 2 column tiles of 16 over W1T
#pragma unroll
    for (int ct = 0; ct < 2; ++ct) {
        f32x4 acc = {0.f, 0.f, 0.f, 0.f};
#pragma unroll
        for (int kt = 0; kt < 4; ++kt) {
            const bf16x8 b = *((const bf16x8*)(W1T + (size_t)(ct * 16 + r) * CIN + kt * 32 + hi * 8));
            acc = __builtin_amdgcn_mfma_f32_16x16x32_bf16(a[kt], b, acc, 0, 0, 0);
        }
        const float bb = b1[ct * 16 + r];
#pragma unroll
        for (int reg = 0; reg < 4; ++reg)
            h_lds[wid][hi * 4 + reg][ct * 16 + r] = fmaxf(acc[reg] + bb, 0.f);
    }
    __syncthreads();

    // M = h @ W2 + b2  (16 verts x 9 outputs per wave)
    for (int idx = lane; idx < 144; idx += 64) {
        const int v = idx / 9, t = idx - v * 9;
        float m = b2[t];
#pragma unroll
        for (int k = 0; k < HID; ++k)
            m = fmaf(h_lds[wid][v][k], W2[k * 9 + t], m);
        M_lds[wid][v][t] = m;
    }
    __syncthreads();

    // Packed symmetric G: t in [0,6) -> (i,j) upper triangle
    for (int idx = lane; idx < 96; idx += 64) {
        const int v = idx / 6, t = idx - v * 6;
        const int i = (t >= 3) + (t >= 5);
        const int j = t - (t >= 3) * 2 - (t >= 5);
        float g = 0.f;
#pragma unroll
        for (int k = 0; k < 3; ++k)
            g += M_lds[wid][v][k * 3 + i] * M_lds[wid][v][k * 3 + j];
        if (v0 + v < N) Gp[(size_t)(v0 + v) * 8 + t] = g;
    }
}

// ---------------------------------------------------------------------------
// Histogram of src; also records each edge's arrival rank within its bucket.
// ---------------------------------------------------------------------------
__global__ void hist_kernel(const int* __restrict__ edges, int* __restrict__ counts,
                            int* __restrict__ rank, int E) {
    const int e = blockIdx.x * blockDim.x + threadIdx.x;
    if (e < E) rank[e] = atomicAdd(&counts[edges[e]], 1);
}

__global__ void blocksum_kernel(const int* __restrict__ counts, int* __restrict__ bsums, int N) {
    __shared__ int s[256];
    const int i = blockIdx.x * 256 + threadIdx.x;
    s[threadIdx.x] = (i < N) ? counts[i] : 0;
    __syncthreads();
    for (int st = 128; st > 0; st >>= 1) {
        if (threadIdx.x < st) s[threadIdx.x] += s[threadIdx.x + st];
        __syncthreads();
    }
    if (threadIdx.x == 0) bsums[blockIdx.x] = s[0];
}

__global__ void scanb_kernel(const int* __restrict__ bsums, int* __restrict__ bpre, int nb) {
    __shared__ int s[256];
    const int t = threadIdx.x;
    const int v0 = (t < nb) ? bsums[t] : 0;
    s[t] = v0;
    __syncthreads();
    for (int off = 1; off < 256; off <<= 1) {
        int v = (t >= off) ? s[t - off] : 0;
        __syncthreads();
        s[t] += v;
        __syncthreads();
    }
    if (t < nb) bpre[t] = s[t] - v0;
}

__global__ void offsets_kernel(const int* __restrict__ counts, const int* __restrict__ bpre,
                               int* __restrict__ offset, int N) {
    __shared__ int s[256];
    const int i = blockIdx.x * 256 + threadIdx.x;
    const int c = (i < N) ? counts[i] : 0;
    s[threadIdx.x] = c;
    __syncthreads();
    for (int off = 1; off < 256; off <<= 1) {
        int v = (threadIdx.x >= off) ? s[threadIdx.x - off] : 0;
        __syncthreads();
        s[threadIdx.x] += v;
        __syncthreads();
    }
    if (i < N) offset[i] = bpre[blockIdx.x] + s[threadIdx.x] - c;
}

// ---------------------------------------------------------------------------
// CSR fill: w = exp(-0.5 (t^T Gs t + t^T Gd t)); scatter packed (dst, w).
// ---------------------------------------------------------------------------
__global__ void fill_kernel(const int* __restrict__ edges,
                            const int* __restrict__ rank,
                            const int* __restrict__ offset,
                            const float* __restrict__ vertsP,  // [N][4]
                            const float* __restrict__ Gp,      // [N][8]
                            int2* __restrict__ dstw,
                            int E) {
    const int e = blockIdx.x * blockDim.x + threadIdx.x;
    if (e >= E) return;
    const int s = edges[e];
    const int d = edges[E + e];

    const float4 vs = ((const float4*)vertsP)[s];
    const float4 vd = ((const float4*)vertsP)[d];
    const float t0 = vd.x - vs.x, t1 = vd.y - vs.y, t2 = vd.z - vs.z;

    const float* gs = Gp + (size_t)s * 8;
    const float* gd = Gp + (size_t)d * 8;
    const float4 ga = ((const float4*)gs)[0];
    const float2 gb = ((const float2*)(gs + 4))[0];
    const float4 ha = ((const float4*)gd)[0];
    const float2 hb = ((const float2*)(gd + 4))[0];

    const float g00 = ga.x + ha.x, g01 = ga.y + ha.y, g02 = ga.z + ha.z;
    const float g11 = ga.w + ha.w, g12 = gb.x + hb.x, g22 = gb.y + hb.y;

    const float q = 0.5f * (g00 * t0 * t0 + g11 * t1 * t1 + g22 * t2 * t2
                  + 2.f * (g01 * t0 * t1 + g02 * t0 * t2 + g12 * t1 * t2));
    const float w = expf(-q);

    const int slot = offset[s] + rank[e];
    dstw[slot] = make_int2(d, __float_as_int(w));
}

// ---------------------------------------------------------------------------
// Gather aggregation: one wave per vertex; lane l owns cols {2l, 2l+1}.
// ---------------------------------------------------------------------------
__global__ __launch_bounds__(256) void agg_kernel(const int* __restrict__ offset,
                                                  const int* __restrict__ counts,
                                                  const int2* __restrict__ dstw,
                                                  const unsigned short* __restrict__ xwb,
                                                  const float* __restrict__ bias,
                                                  float* __restrict__ out,
                                                  int N) {
    const int wid  = threadIdx.x >> 6;
    const int lane = threadIdx.x & 63;
    const int v = blockIdx.x * 4 + wid;
    if (v >= N) return;

    const int2* dw = dstw + offset[v];
    const int deg = counts[v];

    float ax = 0.f, ay = 0.f, wsum = 0.f;
    int k = 0;
    for (; k + 4 <= deg; k += 4) {
        const int2 p0 = dw[k];
        const int2 p1 = dw[k + 1];
        const int2 p2 = dw[k + 2];
        const int2 p3 = dw[k + 3];
        const unsigned u0 = ((const unsigned*)(xwb + (size_t)p0.x * FOUT))[lane];
        const unsigned u1 = ((const unsigned*)(xwb + (size_t)p1.x * FOUT))[lane];
        const unsigned u2 = ((const unsigned*)(xwb + (size_t)p2.x * FOUT))[lane];
        const unsigned u3 = ((const unsigned*)(xwb + (size_t)p3.x * FOUT))[lane];
        const float w0 = __int_as_float(p0.y), w1 = __int_as_float(p1.y);
        const float w2 = __int_as_float(p2.y), w3 = __int_as_float(p3.y);
        ax = fmaf(w0, bfbits2f(u0 & 0xffffu), ax); ay = fmaf(w0, bfbits2f(u0 >> 16), ay);
        ax = fmaf(w1, bfbits2f(u1 & 0xffffu), ax); ay = fmaf(w1, bfbits2f(u1 >> 16), ay);
        ax = fmaf(w2, bfbits2f(u2 & 0xffffu), ax); ay = fmaf(w2, bfbits2f(u2 >> 16), ay);
        ax = fmaf(w3, bfbits2f(u3 & 0xffffu), ax); ay = fmaf(w3, bfbits2f(u3 >> 16), ay);
        wsum += (w0 + w1) + (w2 + w3);
    }
    for (; k < deg; ++k) {
        const int2 p0 = dw[k];
        const unsigned u0 = ((const unsigned*)(xwb + (size_t)p0.x * FOUT))[lane];
        const float w0 = __int_as_float(p0.y);
        ax = fmaf(w0, bfbits2f(u0 & 0xffffu), ax);
        ay = fmaf(w0, bfbits2f(u0 >> 16), ay);
        wsum += w0;
    }

    const float inv = 1.f / (wsum + EPSV);
    const float2 b = ((const float2*)bias)[lane];
    float2 o;
    o.x = ax * inv + b.x;
    o.y = ay * inv + b.y;
    ((float2*)(out + (size_t)v * FOUT))[lane] = o;
}

extern "C" void kernel_launch(void* const* d_in, const int* in_sizes, int n_in,
                              void* d_out, int out_size, void* d_ws, size_t ws_size,
                              hipStream_t stream) {
    const float* feat  = (const float*)d_in[0];
    const float* verts = (const float*)d_in[1];
    const int*   edges = (const int*)d_in[2];
    // d_in[3] = faces (unused)
    const float* W1    = (const float*)d_in[4];
    const float* b1    = (const float*)d_in[5];
    const float* W2    = (const float*)d_in[6];
    const float* b2    = (const float*)d_in[7];
    const float* Wc    = (const float*)d_in[8];
    const float* bias  = (const float*)d_in[9];

    const int N = in_sizes[0] / CIN;
    const int E = in_sizes[2] / 2;
    const int nb = (N + 255) / 256;

    // workspace layout (256B-aligned chunks)
    char* p = (char*)d_ws;
    auto alloc = [&](size_t bytes) {
        char* r = p;
        p += (bytes + 255) & ~(size_t)255;
        return r;
    };
    short*          WcT    = (short*)alloc((size_t)CIN * FOUT * sizeof(short));
    short*          W1T    = (short*)alloc((size_t)HID * CIN * sizeof(short));
    unsigned short* xwb    = (unsigned short*)alloc((size_t)N * FOUT * sizeof(short));
    float*          Gp     = (float*)alloc((size_t)N * 8 * sizeof(float));
    float*          vertsP = (float*)alloc((size_t)N * 4 * sizeof(float));
    int2*           dstw   = (int2*)alloc((size_t)E * sizeof(int2));
    int*            rank   = (int*)alloc((size_t)E * sizeof(int));
    int*            counts = (int*)alloc((size_t)N * sizeof(int));
    int*            offset = (int*)alloc((size_t)N * sizeof(int));
    int*            bsums  = (int*)alloc(256 * sizeof(int));
    int*            bpre   = (int*)alloc(256 * sizeof(int));
    float*          out    = (float*)d_out;

    const int prep_n = (N > CIN * FOUT) ? N : CIN * FOUT;
    prep_kernel<<<(prep_n + 255) / 256, 256, 0, stream>>>(Wc, W1, verts, WcT, W1T, vertsP, counts, N);

    const int nwaves = (N + 15) / 16;
    vertex_mfma<<<(nwaves + 3) / 4, 256, 0, stream>>>(feat, WcT, W1T, b1, W2, b2, Gp, xwb, N);

    hist_kernel<<<(E + 255) / 256, 256, 0, stream>>>(edges, counts, rank, E);
    blocksum_kernel<<<nb, 256, 0, stream>>>(counts, bsums, N);
    scanb_kernel<<<1, 256, 0, stream>>>(bsums, bpre, nb);
    offsets_kernel<<<nb, 256, 0, stream>>>(counts, bpre, offset, N);
    fill_kernel<<<(E + 255) / 256, 256, 0, stream>>>(edges, rank, offset, vertsP, Gp, dstw, E);
    agg_kernel<<<(N + 3) / 4, 256, 0, stream>>>(offset, counts, dstw, xwb, bias, out, N);
}